// Round 1
// baseline (305.764 us; speedup 1.0000x reference)
//
#include <hip/hip_runtime.h>

#define B_ 4
#define N_ 4096
#define D_ 64

typedef __bf16 bf16_t;
typedef bf16_t bf16x8 __attribute__((ext_vector_type(8)));
typedef float f32x16 __attribute__((ext_vector_type(16)));

// Kernel 1: fp32 -> bf16 conversion + per-row squared norms (softmax stabilizer).
// One 64-lane wave per row (D=64): coalesced load, convert, wave-reduce x^2.
__global__ void conv_norm_kernel(const float* __restrict__ X,
                                 bf16_t* __restrict__ Xb,
                                 float* __restrict__ norms) {
    int row = blockIdx.x * 4 + (threadIdx.x >> 6);
    int d   = threadIdx.x & 63;
    size_t idx = (size_t)row * D_ + d;
    float x = X[idx];
    Xb[idx] = (bf16_t)x;
    float sq = x * x;
    #pragma unroll
    for (int off = 32; off; off >>= 1) sq += __shfl_xor(sq, off);
    if (d == 0) norms[row] = sq;
}

// Compute one 32x32 S-tile (K=64) with 4 MFMAs. B-frags straight from global
// (L2-resident: X_b is only 512 KB bf16 per batch).
__device__ __forceinline__ f32x16 tile_mm(const bf16_t* __restrict__ brow,
                                          bf16x8 a0, bf16x8 a1,
                                          bf16x8 a2, bf16x8 a3) {
    bf16x8 b0 = *(const bf16x8*)(brow);
    bf16x8 b1 = *(const bf16x8*)(brow + 16);
    bf16x8 b2 = *(const bf16x8*)(brow + 32);
    bf16x8 b3 = *(const bf16x8*)(brow + 48);
    f32x16 acc;
    #pragma unroll
    for (int i = 0; i < 16; ++i) acc[i] = 0.0f;
    acc = __builtin_amdgcn_mfma_f32_32x32x16_bf16(a0, b0, acc, 0, 0, 0);
    acc = __builtin_amdgcn_mfma_f32_32x32x16_bf16(a1, b1, acc, 0, 0, 0);
    acc = __builtin_amdgcn_mfma_f32_32x32x16_bf16(a2, b2, acc, 0, 0, 0);
    acc = __builtin_amdgcn_mfma_f32_32x32x16_bf16(a3, b3, acc, 0, 0, 0);
    return acc;
}

// Kernel 2: each block owns 32 rows of one batch. Pass 1: row sums of
// exp(s - m). Pass 2: recompute S, write exp(s - lse). A-frags in registers
// for the whole kernel (K=64 fits in 4 frags).
__global__ __launch_bounds__(256) void softmax_xxt_kernel(
        const bf16_t* __restrict__ Xb,
        const float* __restrict__ norms,
        float* __restrict__ Out) {
    const int tid  = threadIdx.x;
    const int wave = tid >> 6;
    const int lane = tid & 63;
    const int b    = blockIdx.x >> 7;          // 128 row-strips per batch
    const int rowbase = (blockIdx.x & 127) * 32;

    const bf16_t* Xbb = Xb + (size_t)b * N_ * D_;
    const int mcol = lane & 31;
    const int half = lane >> 5;

    // A fragments: A[m=lane&31][k=(lane>>5)*8+j], kbase = 0,16,32,48
    const bf16_t* arow = Xbb + (size_t)(rowbase + mcol) * D_ + half * 8;
    const bf16x8 a0 = *(const bf16x8*)(arow);
    const bf16x8 a1 = *(const bf16x8*)(arow + 16);
    const bf16x8 a2 = *(const bf16x8*)(arow + 32);
    const bf16x8 a3 = *(const bf16x8*)(arow + 48);

    // Stabilizer m for the 16 rows this lane's acc regs map to:
    // row = (reg&3) + 8*(reg>>2) + 4*(lane>>5)   [measured m74/m101 C-layout]
    float lse[16];
    {
        const float* nb = norms + b * N_ + rowbase;
        #pragma unroll
        for (int r = 0; r < 16; ++r) {
            int row = (r & 3) + 8 * (r >> 2) + 4 * half;
            lse[r] = nb[row];
        }
    }

    __shared__ float partials[4][32];

    // ---------------- pass 1: denominators ----------------
    float sums[16];
    #pragma unroll
    for (int r = 0; r < 16; ++r) sums[r] = 0.0f;

    for (int t = 0; t < N_ / 128; ++t) {
        const int c0 = t * 128 + wave * 32;   // wave-private 32-col strip
        const bf16_t* brow = Xbb + (size_t)(c0 + mcol) * D_ + half * 8;
        f32x16 acc = tile_mm(brow, a0, a1, a2, a3);
        #pragma unroll
        for (int r = 0; r < 16; ++r) sums[r] += __expf(acc[r] - lse[r]);
    }

    // reduce over the 32 lanes (cols) of each half-wave
    #pragma unroll
    for (int r = 0; r < 16; ++r) {
        float s = sums[r];
        s += __shfl_xor(s, 1);
        s += __shfl_xor(s, 2);
        s += __shfl_xor(s, 4);
        s += __shfl_xor(s, 8);
        s += __shfl_xor(s, 16);
        sums[r] = s;
    }

    // cross-wave combine (each wave covered a different 1024-col span)
    if (mcol == 0) {
        #pragma unroll
        for (int r = 0; r < 16; ++r) {
            int row = (r & 3) + 8 * (r >> 2) + 4 * half;
            partials[wave][row] = sums[r];
        }
    }
    __syncthreads();

    #pragma unroll
    for (int r = 0; r < 16; ++r) {
        int row = (r & 3) + 8 * (r >> 2) + 4 * half;
        float tot = partials[0][row] + partials[1][row] +
                    partials[2][row] + partials[3][row];
        lse[r] += __logf(tot);   // lse = m + log(sum exp(s-m))
    }

    // ---------------- pass 2: recompute + write ----------------
    float* outb = Out + (size_t)b * N_ * N_;
    for (int t = 0; t < N_ / 128; ++t) {
        const int c0 = t * 128 + wave * 32;
        const bf16_t* brow = Xbb + (size_t)(c0 + mcol) * D_ + half * 8;
        f32x16 acc = tile_mm(brow, a0, a1, a2, a3);
        #pragma unroll
        for (int r = 0; r < 16; ++r) {
            int row = rowbase + (r & 3) + 8 * (r >> 2) + 4 * half;
            outb[(size_t)row * N_ + (c0 + mcol)] = __expf(acc[r] - lse[r]);
        }
    }
}

extern "C" void kernel_launch(void* const* d_in, const int* in_sizes, int n_in,
                              void* d_out, int out_size, void* d_ws, size_t ws_size,
                              hipStream_t stream) {
    const float* X = (const float*)d_in[0];
    float* Out     = (float*)d_out;

    bf16_t* Xb   = (bf16_t*)d_ws;                                   // 2 MB
    float*  norms = (float*)((char*)d_ws + (size_t)B_ * N_ * D_ * sizeof(bf16_t)); // 64 KB

    conv_norm_kernel<<<(B_ * N_) / 4, 256, 0, stream>>>(X, Xb, norms);
    softmax_xxt_kernel<<<(B_ * N_) / 32, 256, 0, stream>>>(Xb, norms, Out);
}